// Round 7
// baseline (461.869 us; speedup 1.0000x reference)
//
#include <hip/hip_runtime.h>
#include <stdint.h>

// R7: attn_k — XCD-aware job placement. blockIdx%8 = XCD (round-robin heuristic);
//     XCD x serves only heads {x, x+8, x+16, x+24} -> per-XCD K+V working set = 4MB = L2.
//     K/V stream served by per-XCD L2 (34.5 TB/s) instead of Infinity Cache (~8 TB/s eff),
//     which R6's counters identified as the wall (1.1GB cache reads / 142us, all pipes idle).
//     Within XCD: block g -> stripe (g<32 ? 2g : 127-2g) for complementary per-CU lengths.
//     Everything else identical to R6 (barrier-free, direct-from-global frags).

typedef unsigned short u16;
typedef unsigned int u32;
typedef __attribute__((ext_vector_type(8))) short bf16x8;
typedef __attribute__((ext_vector_type(4))) float f32x4;

#define SEQ 2048
#define DM 2048
#define NH 16
#define HD 128
#define SM_SCALE 0.08838834764831845f
#define K2LOG 0.12751743f   // SM_SCALE * log2(e)

__device__ __forceinline__ u16 f2bf(float f) {
  union { float f; uint32_t u; } v; v.f = f;
  uint32_t u = v.u + 0x7fffu + ((v.u >> 16) & 1u);   // RNE
  return (u16)(u >> 16);
}
__device__ __forceinline__ float bf2f(u16 h) {
  union { uint32_t u; float f; } v; v.u = ((uint32_t)h) << 16; return v.f;
}
__device__ __forceinline__ u32 pack2(float a, float b) {
  return (u32)f2bf(a) | ((u32)f2bf(b) << 16);
}
__device__ __forceinline__ u32 pack2_trunc(float a, float b) {   // RTZ: P in [0,1]
  union { float f; u32 u; } x, y; x.f = a; y.f = b;
  return (x.u >> 16) | (y.u & 0xFFFF0000u);
}

// async global->LDS, 16B per lane (GEMMs only)
__device__ __forceinline__ void gl2lds16(const void* g, void* l) {
  __builtin_amdgcn_global_load_lds(
      (const __attribute__((address_space(1))) uint32_t*)g,
      (__attribute__((address_space(3))) uint32_t*)l, 16, 0, 0);
}

// ---------------- elementwise fp32 -> bf16 of x ----------------
__global__ __launch_bounds__(256) void cvt_x(const float* __restrict__ x, u16* __restrict__ xb) {
  int i = blockIdx.x * 256 + threadIdx.x;
  float4 v = ((const float4*)x)[i];
  uint2 r;
  r.x = pack2(v.x, v.y);
  r.y = pack2(v.z, v.w);
  ((uint2*)xb)[i] = r;
}

// ---------------- W (K,N) fp32 -> Wt (N,K) bf16, tiled transpose ----------------
__global__ __launch_bounds__(256) void wtrans(const float* __restrict__ w0, const float* __restrict__ w1,
                                              const float* __restrict__ w2, const float* __restrict__ w3,
                                              u16* __restrict__ dst) {
  const float* W = blockIdx.z == 0 ? w0 : blockIdx.z == 1 ? w1 : blockIdx.z == 2 ? w2 : w3;
  u16* D = dst + (size_t)blockIdx.z * DM * DM;
  int k0 = blockIdx.x * 32, n0 = blockIdx.y * 32;
  __shared__ u16 t[32][33];
  int tx = threadIdx.x, ty = threadIdx.y;   // (32,8)
#pragma unroll
  for (int i = 0; i < 32; i += 8)
    t[ty + i][tx] = f2bf(W[(size_t)(k0 + ty + i) * DM + n0 + tx]);
  __syncthreads();
#pragma unroll
  for (int i = 0; i < 32; i += 8)
    D[(size_t)(n0 + ty + i) * DM + k0 + tx] = t[tx][ty + i];
}

// ---------------- 128x128 (BK=64) bf16 MFMA GEMM core, global_load_lds staging ----------------
__device__ __forceinline__ void gemm_core(const u16* __restrict__ A, const u16* __restrict__ Bt,
                                          int m0, int n0, u16* As, u16* Bs, f32x4 acc[4][4]) {
  int tid = threadIdx.x, lane = tid & 63;
  int l15 = lane & 15, quad = lane >> 4;
  int wave = tid >> 6;
  int wm = (wave >> 1) * 64, wn = (wave & 1) * 64;
  for (int k0 = 0; k0 < DM; k0 += 64) {
#pragma unroll
    for (int i = 0; i < 4; ++i) {
      int s = i * 256 + tid;
      int row = s >> 3, c = (s & 7) ^ (row & 7);
      gl2lds16(&A[(size_t)(m0 + row) * DM + k0 + c * 8], &As[(s & ~63) * 8]);
      gl2lds16(&Bt[(size_t)(n0 + row) * DM + k0 + c * 8], &Bs[(s & ~63) * 8]);
    }
    __syncthreads();
#pragma unroll
    for (int kk = 0; kk < 2; ++kk) {
      bf16x8 af[4], bfr[4];
#pragma unroll
      for (int mt = 0; mt < 4; ++mt) {
        int row = wm + mt * 16 + l15;
        int c = (kk * 4 + quad) ^ (row & 7);
        af[mt] = *(const bf16x8*)&As[row * 64 + c * 8];
      }
#pragma unroll
      for (int nt = 0; nt < 4; ++nt) {
        int row = wn + nt * 16 + l15;
        int c = (kk * 4 + quad) ^ (row & 7);
        bfr[nt] = *(const bf16x8*)&Bs[row * 64 + c * 8];
      }
#pragma unroll
      for (int mt = 0; mt < 4; ++mt)
#pragma unroll
        for (int nt = 0; nt < 4; ++nt)
          acc[mt][nt] = __builtin_amdgcn_mfma_f32_16x16x32_bf16(af[mt], bfr[nt], acc[mt][nt], 0, 0, 0);
    }
    __syncthreads();
  }
}

// z=0 -> Q, z=1 -> K (row-major bf16), z=2 -> V stored TRANSPOSED into Vt (b,h,d,s)
__global__ __launch_bounds__(256) void qkv_gemm(const u16* __restrict__ X, const u16* __restrict__ Wt,
                                                u16* __restrict__ Qo, u16* __restrict__ Ko,
                                                u16* __restrict__ Vto) {
  __shared__ u16 As[128 * 64];
  __shared__ u16 Bs[128 * 64];
  const u16* Bt = Wt + (size_t)blockIdx.z * DM * DM;
  int n0 = blockIdx.x * 128, m0 = blockIdx.y * 128;
  f32x4 acc[4][4] = {};
  gemm_core(X, Bt, m0, n0, As, Bs, acc);
  int lane = threadIdx.x & 63, wave = threadIdx.x >> 6;
  int l15 = lane & 15, quad = lane >> 4;
  int wm = (wave >> 1) * 64, wn = (wave & 1) * 64;
  if (blockIdx.z == 2) {
    int h = n0 >> 7;
#pragma unroll
    for (int mt = 0; mt < 4; ++mt)
#pragma unroll
      for (int nt = 0; nt < 4; ++nt) {
        int tok = m0 + wm + mt * 16 + quad * 4;
        int d = wn + nt * 16 + l15;
        int b = tok >> 11, sx = tok & (SEQ - 1);
        u16* dp = &Vto[((size_t)(b * NH + h) * HD + d) * SEQ + sx];
        *(u32*)&dp[0] = pack2(acc[mt][nt][0], acc[mt][nt][1]);
        *(u32*)&dp[2] = pack2(acc[mt][nt][2], acc[mt][nt][3]);
      }
  } else {
    u16* C = blockIdx.z == 0 ? Qo : Ko;
#pragma unroll
    for (int mt = 0; mt < 4; ++mt)
#pragma unroll
      for (int nt = 0; nt < 4; ++nt)
#pragma unroll
        for (int r = 0; r < 4; ++r)
          C[(size_t)(m0 + wm + mt * 16 + quad * 4 + r) * DM + n0 + wn + nt * 16 + l15]
              = f2bf(acc[mt][nt][r]);
  }
}

__global__ __launch_bounds__(256) void proj_gemm(const u16* __restrict__ A, const u16* __restrict__ Wt,
                                                 float* __restrict__ C) {
  __shared__ u16 As[128 * 64];
  __shared__ u16 Bs[128 * 64];
  int n0 = blockIdx.x * 128, m0 = blockIdx.y * 128;
  f32x4 acc[4][4] = {};
  gemm_core(A, Wt, m0, n0, As, Bs, acc);
  int lane = threadIdx.x & 63, wave = threadIdx.x >> 6;
  int l15 = lane & 15, quad = lane >> 4;
  int wm = (wave >> 1) * 64, wn = (wave & 1) * 64;
#pragma unroll
  for (int mt = 0; mt < 4; ++mt)
#pragma unroll
    for (int nt = 0; nt < 4; ++nt)
#pragma unroll
      for (int r = 0; r < 4; ++r)
        C[(size_t)(m0 + wm + mt * 16 + quad * 4 + r) * DM + n0 + wn + nt * 16 + l15] = acc[mt][nt][r];
}

// ---------------- RoPE in-place on Q (y=0) and K (y=1), fast sincos ----------------
__global__ __launch_bounds__(256) void rope_k(u16* __restrict__ Q, u16* __restrict__ K,
                                              const int* __restrict__ pos) {
  uint32_t idx = blockIdx.x * 256 + threadIdx.x;
  int i = idx & 63;
  int h = (idx >> 6) & 15;
  int s = (idx >> 10) & 2047;
  int b = idx >> 21;
  u16* P = (blockIdx.y == 0) ? Q : K;
  int p = pos[b * SEQ + s];
  float inv_rev = exp2f(fmaf((float)i, -0.20762051f, -2.6514961f));  // 1e4^(-i/64)/(2pi)
  float pf = (float)p;
  float hi = pf * inv_rev;
  float err = fmaf(pf, inv_rev, -hi);
  float r = (hi - truncf(hi)) + err;
  float ang = r * 6.2831853f;
  float sn = __sinf(ang), cs = __cosf(ang);
  size_t base = ((size_t)(b * SEQ + s)) * DM + h * HD;
  float x1 = bf2f(P[base + i]), x2 = bf2f(P[base + 64 + i]);
  P[base + i] = f2bf(x1 * cs - x2 * sn);
  P[base + 64 + i] = f2bf(x2 * cs + x1 * sn);
}

// ---------------- Flash attention: barrier-free, L2-localized via XCD swizzle ----------------
// blockIdx%8 = XCD x (round-robin heuristic). Wave w of block handles head bh = x + 8w,
// stripe s = (g<32 ? 2g : 127-2g) where g = blockIdx>>3. Per-XCD K+V set = 4 heads = 4MB = L2.
__global__ __launch_bounds__(256, 2) void attn_k(const u16* __restrict__ Q, const u16* __restrict__ K,
                                                 const u16* __restrict__ Vt, const int* __restrict__ pos,
                                                 u16* __restrict__ AO) {
  int tid = threadIdx.x, lane = tid & 63, wave = tid >> 6;
  int x = blockIdx.x & 7;
  int g = blockIdx.x >> 3;                      // [0,64)
  int bh = x + 8 * wave;                        // 4 heads per XCD
  int stripe = (g < 32) ? (2 * g) : (127 - 2 * g);   // complementary per-CU lengths
  int b = bh >> 4, h = bh & 15;
  int l15 = lane & 15, quad = lane >> 4;
  const int* posb = pos + b * SEQ;
  int qbase = stripe * 32;
  const u16* Kbase = &K[(size_t)(b * SEQ) * DM + h * HD];
  const u16* Vbase = &Vt[(size_t)(b * NH + h) * HD * SEQ];

  // Q fragments resident (B-operand layout: n=l15, k=quad*8+j)
  bf16x8 qf[2][4];
#pragma unroll
  for (int qi = 0; qi < 2; ++qi)
#pragma unroll
    for (int kk = 0; kk < 4; ++kk)
      qf[qi][kk] = *(const bf16x8*)&Q[(size_t)(b * SEQ + qbase + qi * 16 + l15) * DM
                                      + h * HD + kk * 32 + quad * 8];

  // sorted positions => visible keys are a prefix [0, cnt)
  auto ub = [&](int v) {
    int c = 0;
#pragma unroll
    for (int st = 1024; st; st >>= 1)
      if (posb[c + st - 1] <= v) c += st;
    if (c == 2047 && posb[2047] <= v) c = 2048;
    return c;
  };
  int cnt[2];
  cnt[0] = ub(posb[qbase + l15]);
  cnt[1] = ub(posb[qbase + 16 + l15]);
  int cnt_min = ub(posb[qbase]);            // wave-uniform
  int cnt_max = ub(posb[qbase + 31]);
  int ntile = (cnt_max + 63) >> 6;

  float m_i[2] = {-1.0e30f, -1.0e30f}, l_i[2] = {0.0f, 0.0f};
  f32x4 oacc[2][8] = {};   // O^T per qi: row d = dt*16+quad*4+r, col q = l15

  int base0 = l15 + ((quad & 1) << 5);
  bool hi_sel = (quad >> 1) != 0;

  for (int j = 0; j < ntile; ++j) {
    int j0 = j * 64;
    // K fragments direct from global: A-frag m=key=kt*16+l15, k=d=kk*32+quad*8..
    bf16x8 kf[4][4];
#pragma unroll
    for (int kk = 0; kk < 4; ++kk)
#pragma unroll
      for (int kt = 0; kt < 4; ++kt)
        kf[kk][kt] = *(const bf16x8*)&Kbase[(size_t)(j0 + kt * 16 + l15) * DM + kk * 32 + quad * 8];

    // S^T[key][q]: sacc[qi][kt] elem r -> key = j0 + kt*16 + quad*4 + r, q = l15
    f32x4 sacc[2][4] = {};
#pragma unroll
    for (int kk = 0; kk < 4; ++kk)
#pragma unroll
      for (int qi = 0; qi < 2; ++qi)
#pragma unroll
        for (int kt = 0; kt < 4; ++kt)
          sacc[qi][kt] = __builtin_amdgcn_mfma_f32_16x16x32_bf16(kf[kk][kt], qf[qi][kk], sacc[qi][kt], 0, 0, 0);

    // V fragments issued BEFORE softmax so their latency hides under the VALU block.
    bf16x8 vf[2][8];
#pragma unroll
    for (int kk2 = 0; kk2 < 2; ++kk2)
#pragma unroll
      for (int dt = 0; dt < 8; ++dt)
        vf[kk2][dt] = *(const bf16x8*)&Vbase[(size_t)(dt * 16 + l15) * SEQ + j0 + kk2 * 32 + quad * 8];

    bool need_mask = (j0 + 64 > cnt_min);   // wave-uniform branch
    u32 pb[2][4][2];
#pragma unroll
    for (int qi = 0; qi < 2; ++qi) {
      if (need_mask) {
        int rel = cnt[qi] - j0;
#pragma unroll
        for (int kt = 0; kt < 4; ++kt)
#pragma unroll
          for (int r = 0; r < 4; ++r)
            if (kt * 16 + quad * 4 + r >= rel) sacc[qi][kt][r] = -1.0e30f;
      }
      float mx = fmaxf(fmaxf(sacc[qi][0][0], sacc[qi][0][1]), fmaxf(sacc[qi][0][2], sacc[qi][0][3]));
#pragma unroll
      for (int kt = 1; kt < 4; ++kt)
        mx = fmaxf(mx, fmaxf(fmaxf(sacc[qi][kt][0], sacc[qi][kt][1]),
                             fmaxf(sacc[qi][kt][2], sacc[qi][kt][3])));
      mx = fmaxf(mx, __shfl_xor(mx, 16));
      mx = fmaxf(mx, __shfl_xor(mx, 32));
      float mold = m_i[qi];
      float mn = fmaxf(mold, mx);
      if (__any(mn > mold)) {
        float al = exp2f((mold - mn) * K2LOG);
        l_i[qi] *= al;
#pragma unroll
        for (int dt = 0; dt < 8; ++dt) oacc[qi][dt] *= al;
        m_i[qi] = mn;
      }
      float nc = -m_i[qi] * K2LOG;
      float rs = 0.0f;
#pragma unroll
      for (int kt = 0; kt < 4; ++kt) {
        float p0 = exp2f(fmaf(sacc[qi][kt][0], K2LOG, nc));
        float p1 = exp2f(fmaf(sacc[qi][kt][1], K2LOG, nc));
        float p2 = exp2f(fmaf(sacc[qi][kt][2], K2LOG, nc));
        float p3 = exp2f(fmaf(sacc[qi][kt][3], K2LOG, nc));
        rs += (p0 + p1) + (p2 + p3);
        pb[qi][kt][0] = pack2_trunc(p0, p1);
        pb[qi][kt][1] = pack2_trunc(p2, p3);
      }
      rs += __shfl_xor(rs, 16);
      rs += __shfl_xor(rs, 32);
      l_i[qi] += rs;
    }

    // O^T += V^T . P^T ; P^T B-frag built via shuffles (verified R5 mapping)
#pragma unroll
    for (int kk2 = 0; kk2 < 2; ++kk2) {
#pragma unroll
      for (int qi = 0; qi < 2; ++qi) {
        u32 w[4];
#pragma unroll
        for (int wd = 0; wd < 4; ++wd) {
          int src = base0 + ((wd >> 1) << 4);
          u32 va = __shfl(pb[qi][kk2 * 2 + 0][wd & 1], src);
          u32 vb = __shfl(pb[qi][kk2 * 2 + 1][wd & 1], src);
          w[wd] = hi_sel ? vb : va;
        }
        union { bf16x8 v; u32 u[4]; } pt;
        pt.u[0] = w[0]; pt.u[1] = w[1]; pt.u[2] = w[2]; pt.u[3] = w[3];
#pragma unroll
        for (int dt = 0; dt < 8; ++dt)
          oacc[qi][dt] = __builtin_amdgcn_mfma_f32_16x16x32_bf16(vf[kk2][dt], pt.v, oacc[qi][dt], 0, 0, 0);
      }
    }
  }

  // epilogue: O[q][d] = O^T / l
#pragma unroll
  for (int qi = 0; qi < 2; ++qi) {
    float inv = 1.0f / l_i[qi];
    u16* aop = &AO[(size_t)(b * SEQ + qbase + qi * 16 + l15) * DM + h * HD];
#pragma unroll
    for (int dt = 0; dt < 8; ++dt) {
      int col = dt * 16 + quad * 4;
      *(u32*)&aop[col]     = pack2(oacc[qi][dt][0] * inv, oacc[qi][dt][1] * inv);
      *(u32*)&aop[col + 2] = pack2(oacc[qi][dt][2] * inv, oacc[qi][dt][3] * inv);
    }
  }
}

extern "C" void kernel_launch(void* const* d_in, const int* in_sizes, int n_in,
                              void* d_out, int out_size, void* d_ws, size_t ws_size,
                              hipStream_t stream) {
  const float* x  = (const float*)d_in[0];
  const float* Wq = (const float*)d_in[1];
  const float* Wk = (const float*)d_in[2];
  const float* Wv = (const float*)d_in[3];
  const float* Wo = (const float*)d_in[4];
  const int*  pos = (const int*)d_in[5];
  float* out = (float*)d_out;

  u16* ws  = (u16*)d_ws;
  u16* xb  = ws;
  u16* wt  = xb  + (size_t)4096 * 2048;
  u16* qb  = wt  + (size_t)4 * 2048 * 2048;
  u16* kb  = qb  + (size_t)4096 * 2048;
  u16* vtb = kb  + (size_t)4096 * 2048;
  u16* aob = vtb + (size_t)4096 * 2048;

  cvt_x<<<8192, 256, 0, stream>>>(x, xb);
  wtrans<<<dim3(64, 64, 4), dim3(32, 8), 0, stream>>>(Wq, Wk, Wv, Wo, wt);
  qkv_gemm<<<dim3(16, 32, 3), 256, 0, stream>>>(xb, wt, qb, kb, vtb);
  rope_k<<<dim3(16384, 2), 256, 0, stream>>>(qb, kb, pos);
  attn_k<<<dim3(512), 256, 0, stream>>>(qb, kb, vtb, pos, aob);
  proj_gemm<<<dim3(16, 32), 256, 0, stream>>>(aob, wt + (size_t)3 * 2048 * 2048, out);
}